// Round 1
// baseline (356.330 us; speedup 1.0000x reference)
//
#include <hip/hip_runtime.h>
#include <math.h>

#define CH 512
#define P 8
#define PLANE 4096   // 64*64
#define EPS 1e-5f

__device__ __forceinline__ float leaky(float x) { return x >= 0.f ? x : 0.01f * x; }

// ---------------- Kernel 1: per-sample predictor params ----------------
// grid = N, block = 256
__global__ __launch_bounds__(256) void predictor_kernel(
    const float* __restrict__ style,   // [N,512,4,4]
    const float* __restrict__ dw_w,    // [8,512,2,2]
    const float* __restrict__ dw_b,    // [8]
    const float* __restrict__ pk_w,    // [8,512]
    const float* __restrict__ pk_b,    // [8]
    const float* __restrict__ pb_w,    // [512,512]
    const float* __restrict__ pb_b,    // [512]
    float* __restrict__ d_pred,        // [N,72]
    float* __restrict__ S_out,         // [N]
    float* __restrict__ bias_out)      // [N,512]
{
    const int n = blockIdx.x;
    const int t = threadIdx.x;
    __shared__ float s_style[512 * 16];   // 32 KB
    __shared__ float s_sd[512];
    __shared__ float s_pk[8];

    const float* sb = style + (size_t)n * 512 * 16;
    for (int i = t; i < 512 * 16; i += 256) s_style[i] = sb[i];
    __syncthreads();

    // s_d = mean over the 4x4 style map
    for (int c = t; c < 512; c += 256) {
        float s = 0.f;
        #pragma unroll
        for (int k = 0; k < 16; ++k) s += s_style[c * 16 + k];
        s_sd[c] = s * (1.f / 16.f);
    }
    __syncthreads();

    // d[n,j,y,x] = leaky(2x2 valid conv + dw_b)
    if (t < 72) {
        int j = t / 9, pos = t % 9, y = pos / 3, x = pos % 3;
        float acc = dw_b[j];
        for (int c = 0; c < 512; ++c) {
            const float* w  = dw_w + (size_t)(j * 512 + c) * 4;
            const float* sp = s_style + c * 16 + y * 4 + x;
            acc += sp[0] * w[0] + sp[1] * w[1] + sp[4] * w[2] + sp[5] * w[3];
        }
        d_pred[n * 72 + t] = leaky(acc);
    }

    // pk[n,o] then S[n] = sum_o pk
    if (t < 8) {
        float acc = pk_b[t];
        const float* w = pk_w + t * 512;
        for (int c = 0; c < 512; ++c) acc += s_sd[c] * w[c];
        s_pk[t] = acc;
    }
    __syncthreads();
    if (t == 0) {
        float s = 0.f;
        #pragma unroll
        for (int o = 0; o < 8; ++o) s += s_pk[o];
        S_out[n] = s;
    }

    // bias[n,c] = s_d . pb_w[c,:] + pb_b[c]
    for (int c = t; c < 512; c += 256) {
        float acc = pb_b[c];
        const float* w = pb_w + (size_t)c * 512;
        for (int cc = 0; cc < 512; ++cc) acc += s_sd[cc] * w[cc];
        bias_out[n * 512 + c] = acc;
    }
}

// ---------------- Kernel 2: per-(n,c) instance-norm stats ----------------
// grid = N*512, block = 256
__global__ __launch_bounds__(256) void stats_kernel(
    const float* __restrict__ content,   // [N,512,64,64]
    float* __restrict__ mean_out,        // [N*512]
    float* __restrict__ rstd_out)        // [N*512]
{
    const int nc = blockIdx.x;
    const int t = threadIdx.x;
    const float4* base = (const float4*)(content + (size_t)nc * PLANE);
    float s = 0.f, sq = 0.f;
    #pragma unroll
    for (int k = 0; k < 4; ++k) {
        float4 v = base[k * 256 + t];
        s  += v.x + v.y + v.z + v.w;
        sq += v.x * v.x + v.y * v.y + v.z * v.z + v.w * v.w;
    }
    #pragma unroll
    for (int off = 32; off > 0; off >>= 1) {
        s  += __shfl_down(s, off, 64);
        sq += __shfl_down(sq, off, 64);
    }
    __shared__ float ls[4], lq[4];
    const int wave = t >> 6, lane = t & 63;
    if (lane == 0) { ls[wave] = s; lq[wave] = sq; }
    __syncthreads();
    if (t == 0) {
        float S = ls[0] + ls[1] + ls[2] + ls[3];
        float Q = lq[0] + lq[1] + lq[2] + lq[3];
        float m = S * (1.f / 4096.f);
        float var = (Q - 4096.f * m * m) * (1.f / 4095.f);  // ddof=1
        mean_out[nc] = m;
        rstd_out[nc] = rsqrtf(var + EPS);
    }
}

// ---------------- Kernel 3: fused group-conv + pointwise-collapse + IN ----------------
// grid = N*64*16 (16 row-tiles of 4 rows), block = 256 (64 wide x 4 rows)
__global__ __launch_bounds__(256) void main_kernel(
    const float* __restrict__ content,   // [N,512,64,64]
    const float* __restrict__ d_pred,    // [N,72]
    const float* __restrict__ S_in,      // [N]
    const float* __restrict__ bias_in,   // [N,512]
    const float* __restrict__ mean_in,   // [N*512]
    const float* __restrict__ rstd_in,   // [N*512]
    float* __restrict__ out)             // [N,512,64,64]
{
    const int b    = blockIdx.x;
    const int tile = b & 15;
    const int g    = (b >> 4) & 63;
    const int n    = b >> 10;
    const int t  = threadIdx.x;
    const int tx = t & 63, ty = t >> 6;
    const int h = tile * 4 + ty, w = tx;

    __shared__ float s_d[72];
    __shared__ float s_S;
    __shared__ float s_bias[8], s_mean[8], s_rstd[8];
    if (t < 72) s_d[t] = d_pred[n * 72 + t];
    if (t == 72) s_S = S_in[n];
    if (t >= 80 && t < 88) {
        int o = t - 80;
        int c = n * 512 + g * 8 + o;
        s_bias[o] = bias_in[c];
        s_mean[o] = mean_in[c];
        s_rstd[o] = rstd_in[c];
    }
    __syncthreads();

    // reflect-pad indices (jnp.pad 'reflect': -1 -> 1, 64 -> 62)
    int rh[3], rw[3];
    #pragma unroll
    for (int k = 0; k < 3; ++k) {
        int y = h - 1 + k;  rh[k] = y < 0 ? -y : (y > 63 ? 126 - y : y);
        int x = w - 1 + k;  rw[k] = x < 0 ? -x : (x > 63 ? 126 - x : x);
    }

    const float* cbase = content + (size_t)(n * 512 + g * 8) * PLANE;
    float xc[8];
    float D = 0.f;
    #pragma unroll
    for (int j = 0; j < 8; ++j) {
        const float* cj = cbase + j * PLANE;
        #pragma unroll
        for (int ky = 0; ky < 3; ++ky) {
            const float* row = cj + rh[ky] * 64;
            #pragma unroll
            for (int kx = 0; kx < 3; ++kx) {
                float v = row[rw[kx]];
                D += v * s_d[j * 9 + ky * 3 + kx];
                if (ky == 1 && kx == 1) xc[j] = v;  // center tap == content[n,c,h,w]
            }
        }
    }

    const float Ds = D * s_S;
    float* obase = out + (size_t)(n * 512 + g * 8) * PLANE + h * 64 + w;
    #pragma unroll
    for (int o = 0; o < 8; ++o) {
        float p = leaky(Ds + s_bias[o]);
        obase[o * PLANE] = (xc[o] - s_mean[o]) * s_rstd[o] * p;
    }
}

extern "C" void kernel_launch(void* const* d_in, const int* in_sizes, int n_in,
                              void* d_out, int out_size, void* d_ws, size_t ws_size,
                              hipStream_t stream) {
    const float* style   = (const float*)d_in[0];
    const float* content = (const float*)d_in[1];
    const float* dw_w    = (const float*)d_in[2];
    const float* dw_b    = (const float*)d_in[3];
    const float* pk_w    = (const float*)d_in[4];
    const float* pk_b    = (const float*)d_in[5];
    const float* pb_w    = (const float*)d_in[6];
    const float* pb_b    = (const float*)d_in[7];
    float* out = (float*)d_out;
    float* ws  = (float*)d_ws;

    const int N = 16;
    float* d_pred  = ws;                  // N*72
    float* S_ws    = d_pred + N * 72;     // N
    float* bias_ws = S_ws + N;            // N*512
    float* mean_ws = bias_ws + N * 512;   // N*512
    float* rstd_ws = mean_ws + N * 512;   // N*512

    predictor_kernel<<<N, 256, 0, stream>>>(style, dw_w, dw_b, pk_w, pk_b,
                                            pb_w, pb_b, d_pred, S_ws, bias_ws);
    stats_kernel<<<N * 512, 256, 0, stream>>>(content, mean_ws, rstd_ws);
    main_kernel<<<N * 64 * 16, 256, 0, stream>>>(content, d_pred, S_ws, bias_ws,
                                                 mean_ws, rstd_ws, out);
}

// Round 2
// 278.845 us; speedup vs baseline: 1.2779x; 1.2779x over previous
//
#include <hip/hip_runtime.h>
#include <math.h>

#define CH 512
#define P 8
#define PLANE 4096   // 64*64
#define EPS 1e-5f

__device__ __forceinline__ float leaky(float x) { return x >= 0.f ? x : 0.01f * x; }

__device__ __forceinline__ float wave_sum(float v) {
    #pragma unroll
    for (int off = 32; off; off >>= 1) v += __shfl_xor(v, off, 64);
    return v;
}

// ---------------- Kernel 1a: s_d means + pk dot + S ----------------
// grid = N, block = 64
__global__ __launch_bounds__(64) void sd_pk_kernel(
    const float* __restrict__ style,   // [N,512,4,4]
    const float* __restrict__ pk_w,    // [8,512]
    const float* __restrict__ pk_b,    // [8]
    float* __restrict__ sd_out,        // [N,512]
    float* __restrict__ S_out)         // [N]
{
    const int n = blockIdx.x;
    const int lane = threadIdx.x;
    const float4* sp = (const float4*)(style + (size_t)n * 8192);
    float sd[8];
    #pragma unroll
    for (int i = 0; i < 8; ++i) {
        int c = lane + 64 * i;
        float4 a = sp[c * 4 + 0], b = sp[c * 4 + 1];
        float4 d = sp[c * 4 + 2], e = sp[c * 4 + 3];
        float s = a.x + a.y + a.z + a.w + b.x + b.y + b.z + b.w
                + d.x + d.y + d.z + d.w + e.x + e.y + e.z + e.w;
        sd[i] = s * (1.f / 16.f);
        sd_out[n * 512 + c] = sd[i];
    }
    float Ssum = 0.f;
    #pragma unroll
    for (int o = 0; o < 8; ++o) {
        float acc = 0.f;
        #pragma unroll
        for (int i = 0; i < 8; ++i)
            acc += pk_w[o * 512 + lane + 64 * i] * sd[i];
        Ssum += wave_sum(acc) + pk_b[o];
    }
    if (lane == 0) S_out[n] = Ssum;
}

// ---------------- Kernel 1b: depthwise-kernel predictor conv ----------------
// one wave per (n, j, tap); grid = 16*72/4 = 288, block = 256
__global__ __launch_bounds__(256) void dconv_kernel(
    const float* __restrict__ style,   // [N,512,4,4]
    const float* __restrict__ dw_w,    // [8,512,2,2]
    const float* __restrict__ dw_b,    // [8]
    float* __restrict__ d_pred)        // [N,72]
{
    const int W = blockIdx.x * 4 + (threadIdx.x >> 6);
    const int lane = threadIdx.x & 63;
    const int n = W / 72, r = W % 72;
    const int j = r / 9, pos = r % 9, y = pos / 3, x = pos % 3;
    const float* sb = style + (size_t)n * 8192;
    const float4* wp = (const float4*)dw_w;
    float acc = 0.f;
    #pragma unroll
    for (int i = 0; i < 8; ++i) {
        int c = lane + 64 * i;
        float4 w = wp[j * 512 + c];
        const float* s = sb + c * 16 + y * 4 + x;
        acc += s[0] * w.x + s[1] * w.y + s[4] * w.z + s[5] * w.w;
    }
    acc = wave_sum(acc);
    if (lane == 0) d_pred[n * 72 + r] = leaky(acc + dw_b[j]);
}

// ---------------- Kernel 1c: bias GEMV ----------------
// one wave per output channel c, all 16 n; grid = 512/4 = 128, block = 256
__global__ __launch_bounds__(256) void bias_kernel(
    const float* __restrict__ sd,      // [N,512]
    const float* __restrict__ pb_w,    // [512,512]
    const float* __restrict__ pb_b,    // [512]
    float* __restrict__ bias_out)      // [N,512]
{
    const int c = blockIdx.x * 4 + (threadIdx.x >> 6);
    const int lane = threadIdx.x & 63;
    float w[8];
    #pragma unroll
    for (int i = 0; i < 8; ++i) w[i] = pb_w[(size_t)c * 512 + lane + 64 * i];
    float acc[16];
    #pragma unroll
    for (int nn = 0; nn < 16; ++nn) acc[nn] = 0.f;
    #pragma unroll
    for (int i = 0; i < 8; ++i) {
        #pragma unroll
        for (int nn = 0; nn < 16; ++nn)
            acc[nn] += w[i] * sd[nn * 512 + lane + 64 * i];
    }
    #pragma unroll
    for (int nn = 0; nn < 16; ++nn) acc[nn] = wave_sum(acc[nn]);
    if (lane == 0) {
        float bb = pb_b[c];
        #pragma unroll
        for (int nn = 0; nn < 16; ++nn) bias_out[nn * 512 + c] = acc[nn] + bb;
    }
}

// ---------------- Kernel 2: per-(n,c) instance-norm stats ----------------
// grid = N*512, block = 256
__global__ __launch_bounds__(256) void stats_kernel(
    const float* __restrict__ content,   // [N,512,64,64]
    float* __restrict__ mean_out,        // [N*512]
    float* __restrict__ rstd_out)        // [N*512]
{
    const int nc = blockIdx.x;
    const int t = threadIdx.x;
    const float4* base = (const float4*)(content + (size_t)nc * PLANE);
    float s = 0.f, sq = 0.f;
    #pragma unroll
    for (int k = 0; k < 4; ++k) {
        float4 v = base[k * 256 + t];
        s  += v.x + v.y + v.z + v.w;
        sq += v.x * v.x + v.y * v.y + v.z * v.z + v.w * v.w;
    }
    #pragma unroll
    for (int off = 32; off > 0; off >>= 1) {
        s  += __shfl_down(s, off, 64);
        sq += __shfl_down(sq, off, 64);
    }
    __shared__ float ls[4], lq[4];
    const int wave = t >> 6, lane = t & 63;
    if (lane == 0) { ls[wave] = s; lq[wave] = sq; }
    __syncthreads();
    if (t == 0) {
        float S = ls[0] + ls[1] + ls[2] + ls[3];
        float Q = lq[0] + lq[1] + lq[2] + lq[3];
        float m = S * (1.f / 4096.f);
        float var = (Q - 4096.f * m * m) * (1.f / 4095.f);  // ddof=1
        mean_out[nc] = m;
        rstd_out[nc] = rsqrtf(var + EPS);
    }
}

// ---------------- Kernel 3: fused conv + pointwise-collapse + IN ----------------
// 4 pixels/thread via float4; halo via shfl. Block = 256 (16x-quads x 16 rows).
// grid = N * 64 groups * 4 row-tiles = 4096
__global__ __launch_bounds__(256) void main_kernel(
    const float* __restrict__ content,   // [N,512,64,64]
    const float* __restrict__ d_pred,    // [N,72]
    const float* __restrict__ S_in,      // [N]
    const float* __restrict__ bias_in,   // [N,512]
    const float* __restrict__ mean_in,   // [N*512]
    const float* __restrict__ rstd_in,   // [N*512]
    float* __restrict__ out)             // [N,512,64,64]
{
    const int b    = blockIdx.x;
    const int tile = b & 3;
    const int g    = (b >> 2) & 63;
    const int n    = b >> 8;
    const int t  = threadIdx.x;
    const int tx = t & 15, ty = t >> 4;
    const int h  = tile * 16 + ty;
    const int x0 = tx * 4;

    __shared__ float s_d[72];
    __shared__ float s_S;
    __shared__ float s_bias[8], s_mean[8], s_rstd[8];
    if (t < 72) s_d[t] = d_pred[n * 72 + t];
    if (t == 80) s_S = S_in[n];
    if (t >= 88 && t < 96) {
        int o = t - 88;
        int c = n * 512 + g * 8 + o;
        s_bias[o] = bias_in[c];
        s_mean[o] = mean_in[c];
        s_rstd[o] = rstd_in[c];
    }
    __syncthreads();

    const float* cbase = content + (size_t)(n * 512 + g * 8) * PLANE;
    float D0 = 0.f, D1 = 0.f, D2 = 0.f, D3 = 0.f;
    float4 xc[8];

    #pragma unroll
    for (int j = 0; j < 8; ++j) {
        const float* cj = cbase + j * PLANE;
        #pragma unroll
        for (int r = 0; r < 3; ++r) {
            int y = h - 1 + r;
            int ry = y < 0 ? 1 : (y > 63 ? 62 : y);   // reflect pad
            float4 v = *(const float4*)(cj + ry * 64 + x0);
            // x-halo from neighbor threads (same row-of-16); edges reflect
            // onto this thread's own vector: x=-1 -> 1 (v.y), x=64 -> 62 (v.z)
            float lv = __shfl_up(v.w, 1, 64);
            float rv = __shfl_down(v.x, 1, 64);
            float xm = (tx == 0)  ? v.y : lv;
            float xp = (tx == 15) ? v.z : rv;
            const float w0 = s_d[j * 9 + r * 3 + 0];
            const float w1 = s_d[j * 9 + r * 3 + 1];
            const float w2 = s_d[j * 9 + r * 3 + 2];
            D0 += w0 * xm  + w1 * v.x + w2 * v.y;
            D1 += w0 * v.x + w1 * v.y + w2 * v.z;
            D2 += w0 * v.y + w1 * v.z + w2 * v.w;
            D3 += w0 * v.z + w1 * v.w + w2 * xp;
            if (r == 1) xc[j] = v;   // center taps == content[n,c,h,x0..x0+3]
        }
    }

    const float S = s_S;
    const float P0 = D0 * S, P1 = D1 * S, P2 = D2 * S, P3 = D3 * S;
    float* obase = out + (size_t)(n * 512 + g * 8) * PLANE + h * 64 + x0;
    #pragma unroll
    for (int o = 0; o < 8; ++o) {
        float bb = s_bias[o], m = s_mean[o], rs = s_rstd[o];
        float4 res;
        res.x = (xc[o].x - m) * rs * leaky(P0 + bb);
        res.y = (xc[o].y - m) * rs * leaky(P1 + bb);
        res.z = (xc[o].z - m) * rs * leaky(P2 + bb);
        res.w = (xc[o].w - m) * rs * leaky(P3 + bb);
        *(float4*)(obase + o * PLANE) = res;
    }
}

extern "C" void kernel_launch(void* const* d_in, const int* in_sizes, int n_in,
                              void* d_out, int out_size, void* d_ws, size_t ws_size,
                              hipStream_t stream) {
    const float* style   = (const float*)d_in[0];
    const float* content = (const float*)d_in[1];
    const float* dw_w    = (const float*)d_in[2];
    const float* dw_b    = (const float*)d_in[3];
    const float* pk_w    = (const float*)d_in[4];
    const float* pk_b    = (const float*)d_in[5];
    const float* pb_w    = (const float*)d_in[6];
    const float* pb_b    = (const float*)d_in[7];
    float* out = (float*)d_out;
    float* ws  = (float*)d_ws;

    const int N = 16;
    float* sd_ws   = ws;                  // N*512
    float* d_pred  = sd_ws + N * 512;     // N*72
    float* S_ws    = d_pred + N * 72;     // N
    float* bias_ws = S_ws + N;            // N*512
    float* mean_ws = bias_ws + N * 512;   // N*512
    float* rstd_ws = mean_ws + N * 512;   // N*512

    sd_pk_kernel<<<N, 64, 0, stream>>>(style, pk_w, pk_b, sd_ws, S_ws);
    dconv_kernel<<<N * 72 / 4, 256, 0, stream>>>(style, dw_w, dw_b, d_pred);
    bias_kernel<<<512 / 4, 256, 0, stream>>>(sd_ws, pb_w, pb_b, bias_ws);
    stats_kernel<<<N * 512, 256, 0, stream>>>(content, mean_ws, rstd_ws);
    main_kernel<<<N * 64 * 4, 256, 0, stream>>>(content, d_pred, S_ws, bias_ws,
                                                mean_ws, rstd_ws, out);
}